// Round 1
// baseline (348.277 us; speedup 1.0000x reference)
//
#include <hip/hip_runtime.h>
#include <hip/hip_bf16.h>

// Shapes (fixed for this problem)
#define S_LEN 1024
#define D_DIM 1024
#define N_BAT 8
#define BSS   (8ull*1024ull*1024ull)   // B*S*S elements per output

using bf16x8 = __attribute__((ext_vector_type(8))) short;
using f32x4  = __attribute__((ext_vector_type(4))) float;

__device__ __forceinline__ short f2bf(float v) {
    __hip_bfloat16 h = __float2bfloat16(v);
    return *reinterpret_cast<short*>(&h);
}

__device__ __forceinline__ void gload_lds16(const void* g, void* l) {
    __builtin_amdgcn_global_load_lds(
        (const __attribute__((address_space(1))) void*)g,
        (__attribute__((address_space(3))) void*)l, 16, 0, 0);
}

// ---------------------------------------------------------------------------
// 1) LayerNorm (unbiased std, eps added to std) -> bf16
//    one block per row of context (8192 rows), 256 threads x 4 elems
// ---------------------------------------------------------------------------
__global__ __launch_bounds__(256) void ln_kernel(
    const float* __restrict__ X, const float* __restrict__ gamma,
    const float* __restrict__ beta, short* __restrict__ Y)
{
    __shared__ float sh[8];
    const size_t row = blockIdx.x;
    const int t = threadIdx.x;
    float4 v = ((const float4*)(X + row * 1024))[t];
    float s  = v.x + v.y + v.z + v.w;
    float ss = v.x*v.x + v.y*v.y + v.z*v.z + v.w*v.w;
    for (int off = 32; off > 0; off >>= 1) {
        s  += __shfl_down(s, off);
        ss += __shfl_down(ss, off);
    }
    const int lane = t & 63, w = t >> 6;
    if (lane == 0) { sh[w] = s; sh[4 + w] = ss; }
    __syncthreads();
    if (t == 0) {
        float S  = sh[0] + sh[1] + sh[2] + sh[3];
        float SS = sh[4] + sh[5] + sh[6] + sh[7];
        float mu = S * (1.0f / 1024.0f);
        float var = fmaxf((SS - S * mu) * (1.0f / 1023.0f), 0.0f);
        sh[0] = mu;
        sh[1] = 1.0f / (sqrtf(var) + 1e-6f);
    }
    __syncthreads();
    const float mu = sh[0], inv = sh[1];
    float4 g  = ((const float4*)gamma)[t];
    float4 be = ((const float4*)beta)[t];
    short4 o;
    o.x = f2bf(g.x * (v.x - mu) * inv + be.x);
    o.y = f2bf(g.y * (v.y - mu) * inv + be.y);
    o.z = f2bf(g.z * (v.z - mu) * inv + be.z);
    o.w = f2bf(g.w * (v.w - mu) * inv + be.w);
    ((short4*)(Y + row * 1024))[t] = o;
}

// ---------------------------------------------------------------------------
// 2) Convert Wk, Wq (f32, [D][D] row-major = [n][k] for x@W.T) -> bf16
// ---------------------------------------------------------------------------
__global__ __launch_bounds__(256) void cvt_kernel(
    const float* __restrict__ Wk, const float* __restrict__ Wq,
    short* __restrict__ wkb, short* __restrict__ wqb)
{
    const size_t i = (size_t)blockIdx.x * 256 + threadIdx.x;
    if (i < 1024ull * 1024ull) {
        wkb[i] = f2bf(Wk[i]);
        wqb[i] = f2bf(Wq[i]);
    }
}

// ---------------------------------------------------------------------------
// 3) Projection GEMM: C[m][n] = sum_k A[m][k]*Bt[n][k] + bias[n]  (bf16 out)
//    m97-style: 128x128 tile, BK=32, 4 waves, mfma 16x16x32 bf16,
//    global_load_lds width=16 staging. M=8192, N=K=1024 fixed strides.
// ---------------------------------------------------------------------------
__global__ __launch_bounds__(256) void gemm_proj(
    const short* __restrict__ A, const short* __restrict__ Bt,
    const float* __restrict__ bias, short* __restrict__ C)
{
    __shared__ short As[128 * 32];
    __shared__ short Bs[128 * 32];
    const int tid  = threadIdx.x;
    const int lane = tid & 63;
    const int w    = tid >> 6;
    const int wr   = w >> 1, wc = w & 1;
    const int brow = blockIdx.x * 128;
    const int bcol = blockIdx.y * 128;

    f32x4 acc[4][4];
#pragma unroll
    for (int m = 0; m < 4; ++m)
#pragma unroll
        for (int n = 0; n < 4; ++n) acc[m][n] = 0.0f;

    for (int k0 = 0; k0 < 1024; k0 += 32) {
#pragma unroll
        for (int c = 0; c < 2; ++c) {
            const int base = w * 2048 + c * 1024;
            const int chunk = base + lane * 16;      // byte offset in 8KB tile
            const int row = chunk >> 6;              // 64 B per 32-elem row
            const int col = (chunk & 63) >> 1;       // bf16 col (0,8,16,24)
            gload_lds16(A  + (size_t)(brow + row) * 1024 + (k0 + col),
                        (char*)As + base);
            gload_lds16(Bt + (size_t)(bcol + row) * 1024 + (k0 + col),
                        (char*)Bs + base);
        }
        __syncthreads();
        bf16x8 af[4], bfr[4];
        const int rsel = lane & 15;
        const int ksel = (lane >> 4) * 8;
#pragma unroll
        for (int m = 0; m < 4; ++m)
            af[m] = *(const bf16x8*)&As[(wr * 64 + m * 16 + rsel) * 32 + ksel];
#pragma unroll
        for (int n = 0; n < 4; ++n)
            bfr[n] = *(const bf16x8*)&Bs[(wc * 64 + n * 16 + rsel) * 32 + ksel];
#pragma unroll
        for (int m = 0; m < 4; ++m)
#pragma unroll
            for (int n = 0; n < 4; ++n)
                acc[m][n] = __builtin_amdgcn_mfma_f32_16x16x32_bf16(
                    af[m], bfr[n], acc[m][n], 0, 0, 0);
        __syncthreads();
    }
#pragma unroll
    for (int m = 0; m < 4; ++m)
#pragma unroll
        for (int n = 0; n < 4; ++n) {
            const int colg = bcol + wc * 64 + n * 16 + (lane & 15);
            const float bv = bias[colg];
#pragma unroll
            for (int r = 0; r < 4; ++r) {
                const int rowg = brow + wr * 64 + m * 16 + ((lane >> 4) * 4 + r);
                C[(size_t)rowg * 1024 + colg] = f2bf(acc[m][n][r] + bv);
            }
        }
}

// ---------------------------------------------------------------------------
// 4) Scores GEMM (per batch): Sc[q][k] = (Q[q].K[k]) / 512   (f32 out)
// ---------------------------------------------------------------------------
__global__ __launch_bounds__(256) void gemm_scores(
    const short* __restrict__ Qm, const short* __restrict__ Km,
    float* __restrict__ Sc)
{
    __shared__ short As[128 * 32];
    __shared__ short Bs[128 * 32];
    const int b = blockIdx.z;
    const short* A  = Qm + (size_t)b * 1024 * 1024;
    const short* Bt = Km + (size_t)b * 1024 * 1024;
    float* C = Sc + (size_t)b * 1024 * 1024;

    const int tid  = threadIdx.x;
    const int lane = tid & 63;
    const int w    = tid >> 6;
    const int wr   = w >> 1, wc = w & 1;
    const int brow = blockIdx.x * 128;
    const int bcol = blockIdx.y * 128;

    f32x4 acc[4][4];
#pragma unroll
    for (int m = 0; m < 4; ++m)
#pragma unroll
        for (int n = 0; n < 4; ++n) acc[m][n] = 0.0f;

    for (int k0 = 0; k0 < 1024; k0 += 32) {
#pragma unroll
        for (int c = 0; c < 2; ++c) {
            const int base = w * 2048 + c * 1024;
            const int chunk = base + lane * 16;
            const int row = chunk >> 6;
            const int col = (chunk & 63) >> 1;
            gload_lds16(A  + (size_t)(brow + row) * 1024 + (k0 + col),
                        (char*)As + base);
            gload_lds16(Bt + (size_t)(bcol + row) * 1024 + (k0 + col),
                        (char*)Bs + base);
        }
        __syncthreads();
        bf16x8 af[4], bfr[4];
        const int rsel = lane & 15;
        const int ksel = (lane >> 4) * 8;
#pragma unroll
        for (int m = 0; m < 4; ++m)
            af[m] = *(const bf16x8*)&As[(wr * 64 + m * 16 + rsel) * 32 + ksel];
#pragma unroll
        for (int n = 0; n < 4; ++n)
            bfr[n] = *(const bf16x8*)&Bs[(wc * 64 + n * 16 + rsel) * 32 + ksel];
#pragma unroll
        for (int m = 0; m < 4; ++m)
#pragma unroll
            for (int n = 0; n < 4; ++n)
                acc[m][n] = __builtin_amdgcn_mfma_f32_16x16x32_bf16(
                    af[m], bfr[n], acc[m][n], 0, 0, 0);
        __syncthreads();
    }
#pragma unroll
    for (int m = 0; m < 4; ++m)
#pragma unroll
        for (int n = 0; n < 4; ++n) {
            const int colg = bcol + wc * 64 + n * 16 + (lane & 15);
#pragma unroll
            for (int r = 0; r < 4; ++r) {
                const int rowg = brow + wr * 64 + m * 16 + ((lane >> 4) * 4 + r);
                C[(size_t)rowg * 1024 + colg] = acc[m][n][r] * 0.001953125f; // /512
            }
        }
}

// ---------------------------------------------------------------------------
// 5) Masked row softmax: block per (b,q) row
// ---------------------------------------------------------------------------
__global__ __launch_bounds__(256) void softmax_kernel(
    const float* __restrict__ Sc, const int* __restrict__ adj,
    float* __restrict__ At)
{
    __shared__ float sh[4];
    const size_t row = blockIdx.x;
    const int t = threadIdx.x;
    const float4 sv = ((const float4*)(Sc + row * 1024))[t];
    const int4   av = ((const int4*)(adj + row * 1024))[t];
    float m = -3.0e38f;
    if (av.x) m = fmaxf(m, sv.x);
    if (av.y) m = fmaxf(m, sv.y);
    if (av.z) m = fmaxf(m, sv.z);
    if (av.w) m = fmaxf(m, sv.w);
    for (int off = 32; off > 0; off >>= 1) m = fmaxf(m, __shfl_down(m, off));
    const int lane = t & 63, w = t >> 6;
    if (lane == 0) sh[w] = m;
    __syncthreads();
    const float M = fmaxf(fmaxf(sh[0], sh[1]), fmaxf(sh[2], sh[3]));
    __syncthreads();
    float e0 = av.x ? expf(sv.x - M) : 0.0f;
    float e1 = av.y ? expf(sv.y - M) : 0.0f;
    float e2 = av.z ? expf(sv.z - M) : 0.0f;
    float e3 = av.w ? expf(sv.w - M) : 0.0f;
    float s = e0 + e1 + e2 + e3;
    for (int off = 32; off > 0; off >>= 1) s += __shfl_down(s, off);
    if (lane == 0) sh[w] = s;
    __syncthreads();
    const float Sm = sh[0] + sh[1] + sh[2] + sh[3];
    float4 o;
    if (Sm > 0.0f) {
        const float inv = 1.0f / Sm;
        o.x = e0 * inv; o.y = e1 * inv; o.z = e2 * inv; o.w = e3 * inv;
    } else {  // all-masked row: jax softmax of equal values -> uniform
        o.x = o.y = o.z = o.w = 1.0f / 1024.0f;
    }
    ((float4*)(At + row * 1024))[t] = o;
}

// ---------------------------------------------------------------------------
// 6) na = prior + (1-prior)*sqrt(attn*attn^T + 1e-9), symmetric, IN-PLACE.
//    Block handles a 32x32 tile-pair (ti<=tj); reads both tiles to LDS first.
// ---------------------------------------------------------------------------
__global__ __launch_bounds__(256) void na_kernel(
    float* __restrict__ At, const float* __restrict__ prior_p)
{
    const int ti = blockIdx.x >> 5, tj = blockIdx.x & 31;
    if (tj < ti) return;
    const int b = blockIdx.y;
    const float prior = *prior_p;
    const float om = 1.0f - prior;
    float* base = At + (size_t)b * 1024 * 1024;
    __shared__ float T1[32][33];
    __shared__ float T2[32][33];
    const int c = threadIdx.x & 31, r0 = threadIdx.x >> 5;
#pragma unroll
    for (int rr = 0; rr < 4; ++rr) {
        const int r = r0 + rr * 8;
        T1[r][c] = base[(size_t)(ti * 32 + r) * 1024 + tj * 32 + c];
        T2[r][c] = base[(size_t)(tj * 32 + r) * 1024 + ti * 32 + c];
    }
    __syncthreads();
#pragma unroll
    for (int rr = 0; rr < 4; ++rr) {
        const int r = r0 + rr * 8;
        const float na1 = prior + om * sqrtf(T1[r][c] * T2[c][r] + 1e-9f);
        base[(size_t)(ti * 32 + r) * 1024 + tj * 32 + c] = na1;
        const float na2 = prior + om * sqrtf(T2[r][c] * T1[c][r] + 1e-9f);
        base[(size_t)(tj * 32 + r) * 1024 + ti * 32 + c] = na2;
    }
}

// ---------------------------------------------------------------------------
// 7) Prefix sums of L[k]=log(na[k,k+1]+1e-9) per batch (f64 accum).
// ---------------------------------------------------------------------------
__global__ void cum_kernel(const float* __restrict__ At, double* __restrict__ cum)
{
    const int b = blockIdx.x;
    if (threadIdx.x != 0) return;
    const float* na = At + (size_t)b * 1024 * 1024;
    double acc = 0.0;
    cum[b * 1024] = 0.0;
    for (int k = 0; k < 1023; ++k) {
        acc += (double)logf(na[(size_t)k * 1024 + (k + 1)] + 1e-9f);
        cum[b * 1024 + k + 1] = acc;
    }
}

// ---------------------------------------------------------------------------
// 8) g_attn fill: diag -> na[i,i]; off-diag -> exp(cum[hi]-cum[lo]) + 1e-9
// ---------------------------------------------------------------------------
__global__ __launch_bounds__(256) void g_kernel(
    const float* __restrict__ At, const double* __restrict__ cum,
    float* __restrict__ G)
{
    const size_t stride = (size_t)gridDim.x * 256;
    for (size_t i = (size_t)blockIdx.x * 256 + threadIdx.x; i < BSS; i += stride) {
        const int b = (int)(i >> 20);
        const int rem = (int)(i & 1048575);
        const int r = rem >> 10, c = rem & 1023;
        float val;
        if (r == c) {
            val = At[i];
        } else {
            const int lo = min(r, c), hi = max(r, c);
            val = expf((float)(cum[b * 1024 + hi] - cum[b * 1024 + lo])) + 1e-9f;
        }
        G[i] = val;
    }
}

// ---------------------------------------------------------------------------
extern "C" void kernel_launch(void* const* d_in, const int* in_sizes, int n_in,
                              void* d_out, int out_size, void* d_ws, size_t ws_size,
                              hipStream_t stream)
{
    const float* context = (const float*)d_in[0];
    // d_in[1] = eos_mask (unused by reference)
    const float* prior   = (const float*)d_in[2];
    const int*   adj     = (const int*)d_in[3];
    const float* Wk      = (const float*)d_in[4];
    const float* bk      = (const float*)d_in[5];
    const float* Wq      = (const float*)d_in[6];
    const float* bq      = (const float*)d_in[7];
    const float* gamma   = (const float*)d_in[8];
    const float* beta    = (const float*)d_in[9];

    float* out   = (float*)d_out;
    float* gout  = out;          // first output: g_attn (scores scratch first)
    float* naout = out + BSS;    // second output: neibor_attn (attn in-place)

    // workspace layout (~52.1 MB)
    char* ws = (char*)d_ws;
    short*  xb   = (short*)(ws);                        // 16 MB  x (bf16)
    short*  wkb  = (short*)(ws + (16ull << 20));        //  2 MB
    short*  wqb  = (short*)(ws + (18ull << 20));        //  2 MB
    short*  keyb = (short*)(ws + (20ull << 20));        // 16 MB
    short*  qryb = (short*)(ws + (36ull << 20));        // 16 MB
    double* cumd = (double*)(ws + (52ull << 20));       // 64 KB

    ln_kernel<<<8192, 256, 0, stream>>>(context, gamma, beta, xb);
    cvt_kernel<<<4096, 256, 0, stream>>>(Wk, Wq, wkb, wqb);
    gemm_proj<<<dim3(64, 8), 256, 0, stream>>>(xb, wkb, bk, keyb);
    gemm_proj<<<dim3(64, 8), 256, 0, stream>>>(xb, wqb, bq, qryb);
    gemm_scores<<<dim3(8, 8, 8), 256, 0, stream>>>(qryb, keyb, gout);
    softmax_kernel<<<8192, 256, 0, stream>>>(gout, adj, naout);
    na_kernel<<<dim3(1024, 8), 256, 0, stream>>>(naout, prior);
    cum_kernel<<<8, 64, 0, stream>>>(naout, cumd);
    g_kernel<<<8192, 256, 0, stream>>>(naout, cumd, gout);
}

// Round 2
// 148.264 us; speedup vs baseline: 2.3490x; 2.3490x over previous
//
#include <hip/hip_runtime.h>
#include <hip/hip_bf16.h>

// Shapes (fixed for this problem)
#define S_LEN 1024
#define D_DIM 1024
#define N_BAT 8
#define BSS   (8ull*1024ull*1024ull)   // B*S*S elements per output

using bf16x8 = __attribute__((ext_vector_type(8))) short;
using f32x4  = __attribute__((ext_vector_type(4))) float;

__device__ __forceinline__ short f2bf(float v) {
    __hip_bfloat16 h = __float2bfloat16(v);
    return *reinterpret_cast<short*>(&h);
}

__device__ __forceinline__ void gload_lds16(const void* g, void* l) {
    __builtin_amdgcn_global_load_lds(
        (const __attribute__((address_space(1))) void*)g,
        (__attribute__((address_space(3))) void*)l, 16, 0, 0);
}

// ---------------------------------------------------------------------------
// 1) LayerNorm (unbiased std, eps added to std) -> bf16
//    one block per row of context (8192 rows), 256 threads x 4 elems
// ---------------------------------------------------------------------------
__global__ __launch_bounds__(256) void ln_kernel(
    const float* __restrict__ X, const float* __restrict__ gamma,
    const float* __restrict__ beta, short* __restrict__ Y)
{
    __shared__ float sh[8];
    const size_t row = blockIdx.x;
    const int t = threadIdx.x;
    float4 v = ((const float4*)(X + row * 1024))[t];
    float s  = v.x + v.y + v.z + v.w;
    float ss = v.x*v.x + v.y*v.y + v.z*v.z + v.w*v.w;
    for (int off = 32; off > 0; off >>= 1) {
        s  += __shfl_down(s, off);
        ss += __shfl_down(ss, off);
    }
    const int lane = t & 63, w = t >> 6;
    if (lane == 0) { sh[w] = s; sh[4 + w] = ss; }
    __syncthreads();
    if (t == 0) {
        float S  = sh[0] + sh[1] + sh[2] + sh[3];
        float SS = sh[4] + sh[5] + sh[6] + sh[7];
        float mu = S * (1.0f / 1024.0f);
        float var = fmaxf((SS - S * mu) * (1.0f / 1023.0f), 0.0f);
        sh[0] = mu;
        sh[1] = 1.0f / (sqrtf(var) + 1e-6f);
    }
    __syncthreads();
    const float mu = sh[0], inv = sh[1];
    float4 g  = ((const float4*)gamma)[t];
    float4 be = ((const float4*)beta)[t];
    short4 o;
    o.x = f2bf(g.x * (v.x - mu) * inv + be.x);
    o.y = f2bf(g.y * (v.y - mu) * inv + be.y);
    o.z = f2bf(g.z * (v.z - mu) * inv + be.z);
    o.w = f2bf(g.w * (v.w - mu) * inv + be.w);
    ((short4*)(Y + row * 1024))[t] = o;
}

// ---------------------------------------------------------------------------
// 2) Convert Wk, Wq (f32, [D][D] row-major = [n][k] for x@W.T) -> bf16
// ---------------------------------------------------------------------------
__global__ __launch_bounds__(256) void cvt_kernel(
    const float* __restrict__ Wk, const float* __restrict__ Wq,
    short* __restrict__ wkb, short* __restrict__ wqb)
{
    const size_t i = (size_t)blockIdx.x * 256 + threadIdx.x;
    if (i < 1024ull * 1024ull) {
        wkb[i] = f2bf(Wk[i]);
        wqb[i] = f2bf(Wq[i]);
    }
}

// ---------------------------------------------------------------------------
// 3) Projection GEMM: C[m][n] = sum_k A[m][k]*Bt[n][k] + bias[n]  (bf16 out)
//    m97-style: 128x128 tile, BK=32, 4 waves, mfma 16x16x32 bf16,
//    global_load_lds width=16 staging. M=8192, N=K=1024 fixed strides.
// ---------------------------------------------------------------------------
__global__ __launch_bounds__(256) void gemm_proj(
    const short* __restrict__ A, const short* __restrict__ Bt,
    const float* __restrict__ bias, short* __restrict__ C)
{
    __shared__ short As[128 * 32];
    __shared__ short Bs[128 * 32];
    const int tid  = threadIdx.x;
    const int lane = tid & 63;
    const int w    = tid >> 6;
    const int wr   = w >> 1, wc = w & 1;
    const int brow = blockIdx.x * 128;
    const int bcol = blockIdx.y * 128;

    f32x4 acc[4][4];
#pragma unroll
    for (int m = 0; m < 4; ++m)
#pragma unroll
        for (int n = 0; n < 4; ++n) acc[m][n] = 0.0f;

    for (int k0 = 0; k0 < 1024; k0 += 32) {
#pragma unroll
        for (int c = 0; c < 2; ++c) {
            const int base = w * 2048 + c * 1024;
            const int chunk = base + lane * 16;      // byte offset in 8KB tile
            const int row = chunk >> 6;              // 64 B per 32-elem row
            const int col = (chunk & 63) >> 1;       // bf16 col (0,8,16,24)
            gload_lds16(A  + (size_t)(brow + row) * 1024 + (k0 + col),
                        (char*)As + base);
            gload_lds16(Bt + (size_t)(bcol + row) * 1024 + (k0 + col),
                        (char*)Bs + base);
        }
        __syncthreads();
        bf16x8 af[4], bfr[4];
        const int rsel = lane & 15;
        const int ksel = (lane >> 4) * 8;
#pragma unroll
        for (int m = 0; m < 4; ++m)
            af[m] = *(const bf16x8*)&As[(wr * 64 + m * 16 + rsel) * 32 + ksel];
#pragma unroll
        for (int n = 0; n < 4; ++n)
            bfr[n] = *(const bf16x8*)&Bs[(wc * 64 + n * 16 + rsel) * 32 + ksel];
#pragma unroll
        for (int m = 0; m < 4; ++m)
#pragma unroll
            for (int n = 0; n < 4; ++n)
                acc[m][n] = __builtin_amdgcn_mfma_f32_16x16x32_bf16(
                    af[m], bfr[n], acc[m][n], 0, 0, 0);
        __syncthreads();
    }
#pragma unroll
    for (int m = 0; m < 4; ++m)
#pragma unroll
        for (int n = 0; n < 4; ++n) {
            const int colg = bcol + wc * 64 + n * 16 + (lane & 15);
            const float bv = bias[colg];
#pragma unroll
            for (int r = 0; r < 4; ++r) {
                const int rowg = brow + wr * 64 + m * 16 + ((lane >> 4) * 4 + r);
                C[(size_t)rowg * 1024 + colg] = f2bf(acc[m][n][r] + bv);
            }
        }
}

// ---------------------------------------------------------------------------
// 4) Scores GEMM (per batch): Sc[q][k] = (Q[q].K[k]) / 512   (f32 out)
// ---------------------------------------------------------------------------
__global__ __launch_bounds__(256) void gemm_scores(
    const short* __restrict__ Qm, const short* __restrict__ Km,
    float* __restrict__ Sc)
{
    __shared__ short As[128 * 32];
    __shared__ short Bs[128 * 32];
    const int b = blockIdx.z;
    const short* A  = Qm + (size_t)b * 1024 * 1024;
    const short* Bt = Km + (size_t)b * 1024 * 1024;
    float* C = Sc + (size_t)b * 1024 * 1024;

    const int tid  = threadIdx.x;
    const int lane = tid & 63;
    const int w    = tid >> 6;
    const int wr   = w >> 1, wc = w & 1;
    const int brow = blockIdx.x * 128;
    const int bcol = blockIdx.y * 128;

    f32x4 acc[4][4];
#pragma unroll
    for (int m = 0; m < 4; ++m)
#pragma unroll
        for (int n = 0; n < 4; ++n) acc[m][n] = 0.0f;

    for (int k0 = 0; k0 < 1024; k0 += 32) {
#pragma unroll
        for (int c = 0; c < 2; ++c) {
            const int base = w * 2048 + c * 1024;
            const int chunk = base + lane * 16;
            const int row = chunk >> 6;
            const int col = (chunk & 63) >> 1;
            gload_lds16(A  + (size_t)(brow + row) * 1024 + (k0 + col),
                        (char*)As + base);
            gload_lds16(Bt + (size_t)(bcol + row) * 1024 + (k0 + col),
                        (char*)Bs + base);
        }
        __syncthreads();
        bf16x8 af[4], bfr[4];
        const int rsel = lane & 15;
        const int ksel = (lane >> 4) * 8;
#pragma unroll
        for (int m = 0; m < 4; ++m)
            af[m] = *(const bf16x8*)&As[(wr * 64 + m * 16 + rsel) * 32 + ksel];
#pragma unroll
        for (int n = 0; n < 4; ++n)
            bfr[n] = *(const bf16x8*)&Bs[(wc * 64 + n * 16 + rsel) * 32 + ksel];
#pragma unroll
        for (int m = 0; m < 4; ++m)
#pragma unroll
            for (int n = 0; n < 4; ++n)
                acc[m][n] = __builtin_amdgcn_mfma_f32_16x16x32_bf16(
                    af[m], bfr[n], acc[m][n], 0, 0, 0);
        __syncthreads();
    }
#pragma unroll
    for (int m = 0; m < 4; ++m)
#pragma unroll
        for (int n = 0; n < 4; ++n) {
            const int colg = bcol + wc * 64 + n * 16 + (lane & 15);
#pragma unroll
            for (int r = 0; r < 4; ++r) {
                const int rowg = brow + wr * 64 + m * 16 + ((lane >> 4) * 4 + r);
                C[(size_t)rowg * 1024 + colg] = acc[m][n][r] * 0.001953125f; // /512
            }
        }
}

// ---------------------------------------------------------------------------
// 5) Masked row softmax: block per (b,q) row
// ---------------------------------------------------------------------------
__global__ __launch_bounds__(256) void softmax_kernel(
    const float* __restrict__ Sc, const int* __restrict__ adj,
    float* __restrict__ At)
{
    __shared__ float sh[4];
    const size_t row = blockIdx.x;
    const int t = threadIdx.x;
    const float4 sv = ((const float4*)(Sc + row * 1024))[t];
    const int4   av = ((const int4*)(adj + row * 1024))[t];
    float m = -3.0e38f;
    if (av.x) m = fmaxf(m, sv.x);
    if (av.y) m = fmaxf(m, sv.y);
    if (av.z) m = fmaxf(m, sv.z);
    if (av.w) m = fmaxf(m, sv.w);
    for (int off = 32; off > 0; off >>= 1) m = fmaxf(m, __shfl_down(m, off));
    const int lane = t & 63, w = t >> 6;
    if (lane == 0) sh[w] = m;
    __syncthreads();
    const float M = fmaxf(fmaxf(sh[0], sh[1]), fmaxf(sh[2], sh[3]));
    __syncthreads();
    float e0 = av.x ? expf(sv.x - M) : 0.0f;
    float e1 = av.y ? expf(sv.y - M) : 0.0f;
    float e2 = av.z ? expf(sv.z - M) : 0.0f;
    float e3 = av.w ? expf(sv.w - M) : 0.0f;
    float s = e0 + e1 + e2 + e3;
    for (int off = 32; off > 0; off >>= 1) s += __shfl_down(s, off);
    if (lane == 0) sh[w] = s;
    __syncthreads();
    const float Sm = sh[0] + sh[1] + sh[2] + sh[3];
    float4 o;
    if (Sm > 0.0f) {
        const float inv = 1.0f / Sm;
        o.x = e0 * inv; o.y = e1 * inv; o.z = e2 * inv; o.w = e3 * inv;
    } else {  // all-masked row: jax softmax of equal values -> uniform
        o.x = o.y = o.z = o.w = 1.0f / 1024.0f;
    }
    ((float4*)(At + row * 1024))[t] = o;
}

// ---------------------------------------------------------------------------
// 6) na = prior + (1-prior)*sqrt(attn*attn^T + 1e-9), symmetric, IN-PLACE.
//    Block handles a 32x32 tile-pair (ti<=tj); reads both tiles to LDS first.
// ---------------------------------------------------------------------------
__global__ __launch_bounds__(256) void na_kernel(
    float* __restrict__ At, const float* __restrict__ prior_p)
{
    const int ti = blockIdx.x >> 5, tj = blockIdx.x & 31;
    if (tj < ti) return;
    const int b = blockIdx.y;
    const float prior = *prior_p;
    const float om = 1.0f - prior;
    float* base = At + (size_t)b * 1024 * 1024;
    __shared__ float T1[32][33];
    __shared__ float T2[32][33];
    const int c = threadIdx.x & 31, r0 = threadIdx.x >> 5;
#pragma unroll
    for (int rr = 0; rr < 4; ++rr) {
        const int r = r0 + rr * 8;
        T1[r][c] = base[(size_t)(ti * 32 + r) * 1024 + tj * 32 + c];
        T2[r][c] = base[(size_t)(tj * 32 + r) * 1024 + ti * 32 + c];
    }
    __syncthreads();
#pragma unroll
    for (int rr = 0; rr < 4; ++rr) {
        const int r = r0 + rr * 8;
        const float na1 = prior + om * sqrtf(T1[r][c] * T2[c][r] + 1e-9f);
        base[(size_t)(ti * 32 + r) * 1024 + tj * 32 + c] = na1;
        const float na2 = prior + om * sqrtf(T2[r][c] * T1[c][r] + 1e-9f);
        base[(size_t)(tj * 32 + r) * 1024 + ti * 32 + c] = na2;
    }
}

// ---------------------------------------------------------------------------
// 7) Prefix sums of L[k]=log(na[k,k+1]+1e-9) per batch.
//    Parallel: one 1024-thread block per batch; f64 Hillis-Steele scan in LDS.
//    cum[b][t] = sum_{k<t} log(na[k,k+1]+1e-9)   (cum[b][0] = 0)
// ---------------------------------------------------------------------------
__global__ __launch_bounds__(1024) void cum_kernel(
    const float* __restrict__ At, double* __restrict__ cum)
{
    __shared__ double sh[1024];
    const int b = blockIdx.x;
    const int t = threadIdx.x;
    const float* na = At + (size_t)b * 1024 * 1024;
    double v = 0.0;
    if (t >= 1) {
        const int k = t - 1;   // superdiagonal element na[k][k+1]
        v = (double)logf(na[(size_t)k * 1024 + (k + 1)] + 1e-9f);
    }
    sh[t] = v;
    __syncthreads();
#pragma unroll
    for (int off = 1; off < 1024; off <<= 1) {
        const double add = (t >= off) ? sh[t - off] : 0.0;
        __syncthreads();
        sh[t] += add;
        __syncthreads();
    }
    cum[b * 1024 + t] = sh[t];
}

// ---------------------------------------------------------------------------
// 8) g_attn fill: diag -> na[i,i]; off-diag -> exp(cum[hi]-cum[lo]) + 1e-9
// ---------------------------------------------------------------------------
__global__ __launch_bounds__(256) void g_kernel(
    const float* __restrict__ At, const double* __restrict__ cum,
    float* __restrict__ G)
{
    const size_t stride = (size_t)gridDim.x * 256;
    for (size_t i = (size_t)blockIdx.x * 256 + threadIdx.x; i < BSS; i += stride) {
        const int b = (int)(i >> 20);
        const int rem = (int)(i & 1048575);
        const int r = rem >> 10, c = rem & 1023;
        float val;
        if (r == c) {
            val = At[i];
        } else {
            const int lo = min(r, c), hi = max(r, c);
            val = expf((float)(cum[b * 1024 + hi] - cum[b * 1024 + lo])) + 1e-9f;
        }
        G[i] = val;
    }
}

// ---------------------------------------------------------------------------
extern "C" void kernel_launch(void* const* d_in, const int* in_sizes, int n_in,
                              void* d_out, int out_size, void* d_ws, size_t ws_size,
                              hipStream_t stream)
{
    const float* context = (const float*)d_in[0];
    // d_in[1] = eos_mask (unused by reference)
    const float* prior   = (const float*)d_in[2];
    const int*   adj     = (const int*)d_in[3];
    const float* Wk      = (const float*)d_in[4];
    const float* bk      = (const float*)d_in[5];
    const float* Wq      = (const float*)d_in[6];
    const float* bq      = (const float*)d_in[7];
    const float* gamma   = (const float*)d_in[8];
    const float* beta    = (const float*)d_in[9];

    float* out   = (float*)d_out;
    float* gout  = out;          // first output: g_attn (scores scratch first)
    float* naout = out + BSS;    // second output: neibor_attn (attn in-place)

    // workspace layout (~52.1 MB)
    char* ws = (char*)d_ws;
    short*  xb   = (short*)(ws);                        // 16 MB  x (bf16)
    short*  wkb  = (short*)(ws + (16ull << 20));        //  2 MB
    short*  wqb  = (short*)(ws + (18ull << 20));        //  2 MB
    short*  keyb = (short*)(ws + (20ull << 20));        // 16 MB
    short*  qryb = (short*)(ws + (36ull << 20));        // 16 MB
    double* cumd = (double*)(ws + (52ull << 20));       // 64 KB

    ln_kernel<<<8192, 256, 0, stream>>>(context, gamma, beta, xb);
    cvt_kernel<<<4096, 256, 0, stream>>>(Wk, Wq, wkb, wqb);
    gemm_proj<<<dim3(64, 8), 256, 0, stream>>>(xb, wkb, bk, keyb);
    gemm_proj<<<dim3(64, 8), 256, 0, stream>>>(xb, wqb, bq, qryb);
    gemm_scores<<<dim3(8, 8, 8), 256, 0, stream>>>(qryb, keyb, gout);
    softmax_kernel<<<8192, 256, 0, stream>>>(gout, adj, naout);
    na_kernel<<<dim3(1024, 8), 256, 0, stream>>>(naout, prior);
    cum_kernel<<<8, 1024, 0, stream>>>(naout, cumd);
    g_kernel<<<8192, 256, 0, stream>>>(naout, cumd, gout);
}